// Round 8
// baseline (242.156 us; speedup 1.0000x reference)
//
#include <hip/hip_runtime.h>
#include <hip/hip_bf16.h>

#define NB    512   // sequence length N
#define DB    512   // model dim D
#define EB    64    // d_dir
#define JT    16    // j-rows per tile (tile = 16 x 512 = 32KB out)
#define STEPS 32    // tiles per block
#define GRID  1024  // exactly-resident persistent grid (4 blocks/CU)

typedef __bf16 bf16x8 __attribute__((ext_vector_type(8)));
typedef float  f32x4  __attribute__((ext_vector_type(4)));

// ---- Kernel A: q = t@Wq^T, k = t@Wk^T, rounded to bf16. 1 wave per (b,n). ----
__global__ __launch_bounds__(64) void qk_proj_bf16(
    const float* __restrict__ t,    // (B*N, 512)
    const float* __restrict__ Wq,   // (64, 512)
    const float* __restrict__ Wk,   // (64, 512)
    __bf16* __restrict__ qb,        // (B*N, 64)
    __bf16* __restrict__ kb)        // (B*N, 64)
{
    __shared__ float trow[DB];
    const int bn = blockIdx.x;
    const int e  = threadIdx.x;     // 0..63
    #pragma unroll
    for (int idx = 0; idx < DB / 64; ++idx)
        trow[idx * 64 + e] = t[(size_t)bn * DB + idx * 64 + e];
    __syncthreads();

    float aq = 0.f, ak = 0.f;
    const float* wqr = Wq + (size_t)e * DB;
    const float* wkr = Wk + (size_t)e * DB;
    #pragma unroll 8
    for (int d = 0; d < DB; ++d) {
        const float tv = trow[d];
        aq += tv * wqr[d];
        ak += tv * wkr[d];
    }
    qb[bn * EB + e] = (__bf16)aq;
    kb[bn * EB + e] = (__bf16)ak;
}

// ---- tiny: Wv fp32 -> bf16 ----
__global__ void wv_to_bf16(const float* __restrict__ Wv, __bf16* __restrict__ wvb, int n)
{
    int i = blockIdx.x * blockDim.x + threadIdx.x;
    if (i < n) wvb[i] = (__bf16)Wv[i];
}

// ---- Kernel B (persistent, barrier-free, INTERLEAVED tile mapping): ----
// out[b,i,j,d] = sum_e (k[b,j,e]*q[b,i,e]) * Wv[d,e]
// Step s, block bid -> tile_id = s*GRID + bid; out addr = tile_id * 32KB.
// => GPU-wide store stream is ONE contiguous 32MB window marching linearly
//    (fillBuffer's DRAM-row-friendly pattern).
// Decode: bi = tile_id>>5, jt = tile_id&31 = bid&31 (constant per block).
// Per step: reload q row (L1-hot 128B), fold into k, 16 MFMA, wave-private
// swizzled LDS transpose, 512B-segment stores. No __syncthreads anywhere.
__global__ __launch_bounds__(256) void kappa_mfma(
    const __bf16* __restrict__ qb,   // (B*N, 64)
    const __bf16* __restrict__ kb,   // (B*N, 64)
    const __bf16* __restrict__ wvb,  // (512, 64)  [d][e]
    float* __restrict__ out)         // (B*N * N * 512)
{
    const int bid = blockIdx.x;          // 0..1023
    const int jt  = bid & 31;            // j-tile, constant per block
    const int q0  = bid >> 5;            // bi base
    const int w    = threadIdx.x >> 6;   // wave 0..3 -> d-quarter
    const int l    = threadIdx.x & 63;
    const int lrow = l & 15;
    const int lgrp = l >> 4;             // e-chunk base = lgrp*8
    const int dbase = w * 128;

    __shared__ float lds[4 * JT * 128];  // 32 KB total; 8 KB per wave
    float* __restrict__ wtile = lds + w * (JT * 128);

    // Raw Wv fragments (MFMA A operand, m=d): loaded once. L2-hit.
    bf16x8 bfrag[8][2];
    #pragma unroll
    for (int df = 0; df < 8; ++df) {
        const int d = dbase + df * 16 + lrow;
        #pragma unroll
        for (int ks = 0; ks < 2; ++ks)
            bfrag[df][ks] = *reinterpret_cast<const bf16x8*>(
                wvb + (size_t)d * EB + ks * 32 + lgrp * 8);
    }

    const int jrow = jt * JT + lrow;     // k row within batch, constant

    // prefetch step 0: bi = q0, b = q0>>9
    int bi = q0;
    bf16x8 qv0 = *reinterpret_cast<const bf16x8*>(qb + (size_t)bi * EB + lgrp * 8);
    bf16x8 qv1 = *reinterpret_cast<const bf16x8*>(qb + (size_t)bi * EB + 32 + lgrp * 8);
    bf16x8 kv0 = *reinterpret_cast<const bf16x8*>(kb + ((size_t)(bi >> 9) * NB + jrow) * EB + lgrp * 8);
    bf16x8 kv1 = *reinterpret_cast<const bf16x8*>(kb + ((size_t)(bi >> 9) * NB + jrow) * EB + 32 + lgrp * 8);

    const int r_lo = l >> 5;        // 0/1: epilogue row parity
    const int cc   = l & 31;        // epilogue d-chunk (16B units)

    for (int s = 0; s < STEPS; ++s) {
        const int tile_id = s * GRID + bid;

        // fold q into k  (a[e] = k[j,e]*q[i,e])
        bf16x8 a0, a1;
        #pragma unroll
        for (int x = 0; x < 8; ++x) {
            a0[x] = (__bf16)((float)kv0[x] * (float)qv0[x]);
            a1[x] = (__bf16)((float)kv1[x] * (float)qv1[x]);
        }

        // MFMA (m=d): acc[df][r] = out[j=jt*16+lrow][d=dbase+df*16+lgrp*4+r]
        f32x4 acc[8];
        #pragma unroll
        for (int df = 0; df < 8; ++df) {
            acc[df] = (f32x4){0.f, 0.f, 0.f, 0.f};
            acc[df] = __builtin_amdgcn_mfma_f32_16x16x32_bf16(bfrag[df][0], a0, acc[df], 0, 0, 0);
            acc[df] = __builtin_amdgcn_mfma_f32_16x16x32_bf16(bfrag[df][1], a1, acc[df], 0, 0, 0);
        }

        // prefetch q,k for next step (uniform branch; bi advances by 32)
        if (s + 1 < STEPS) {
            const int bin = (s + 1) * (GRID >> 5) + q0;   // = s*32 + 32 + q0
            qv0 = *reinterpret_cast<const bf16x8*>(qb + (size_t)bin * EB + lgrp * 8);
            qv1 = *reinterpret_cast<const bf16x8*>(qb + (size_t)bin * EB + 32 + lgrp * 8);
            kv0 = *reinterpret_cast<const bf16x8*>(kb + ((size_t)(bin >> 9) * NB + jrow) * EB + lgrp * 8);
            kv1 = *reinterpret_cast<const bf16x8*>(kb + ((size_t)(bin >> 9) * NB + jrow) * EB + 32 + lgrp * 8);
        }

        // acc -> wave-private LDS, XOR-16B swizzle (uniform bank spread)
        asm volatile("" ::: "memory");
        #pragma unroll
        for (int df = 0; df < 8; ++df) {
            const int sc = (df * 4 + lgrp) ^ (lrow & 7);
            *reinterpret_cast<f32x4*>(wtile + lrow * 128 + sc * 4) = acc[df];
        }
        asm volatile("" ::: "memory");

        // read back + store: per pass 2 rows x 512B contiguous segments.
        // out flat addr = tile_id*8192 floats (GPU-wide linear march).
        float* __restrict__ obase = out + (size_t)tile_id * (JT * DB) + dbase;
        #pragma unroll
        for (int p = 0; p < 8; ++p) {
            const int r  = 2 * p + r_lo;
            const int sc = cc ^ (r & 7);
            const f32x4 v = *reinterpret_cast<const f32x4*>(wtile + r * 128 + sc * 4);
            *reinterpret_cast<f32x4*>(obase + (size_t)r * DB + cc * 4) = v;
        }
    }
}

extern "C" void kernel_launch(void* const* d_in, const int* in_sizes, int n_in,
                              void* d_out, int out_size, void* d_ws, size_t ws_size,
                              hipStream_t stream) {
    const float* t  = (const float*)d_in[0];  // (2,512,512)
    const float* Wq = (const float*)d_in[1];  // (64,512)
    const float* Wk = (const float*)d_in[2];  // (64,512)
    const float* Wv = (const float*)d_in[3];  // (512,64)
    float* out = (float*)d_out;

    const int B = 2;

    __bf16* qb  = (__bf16*)d_ws;                       // B*N*64
    __bf16* kbf = qb + (size_t)B * NB * EB;            // B*N*64
    __bf16* wvb = kbf + (size_t)B * NB * EB;           // 512*64

    qk_proj_bf16<<<dim3(B * NB), dim3(64), 0, stream>>>(t, Wq, Wk, qb, kbf);
    wv_to_bf16<<<dim3((DB * EB + 255) / 256), dim3(256), 0, stream>>>(Wv, wvb, DB * EB);

    kappa_mfma<<<dim3(GRID), dim3(256), 0, stream>>>(qb, kbf, wvb, out);
}

// Round 9
// 241.415 us; speedup vs baseline: 1.0031x; 1.0031x over previous
//
#include <hip/hip_runtime.h>
#include <hip/hip_bf16.h>

#define NB   512   // sequence length N
#define DB   512   // model dim D
#define EB   64    // d_dir
#define JT   16    // j-rows per tile
#define TPB  16    // tiles per block (block covers 256 rows = half a bi)

typedef __bf16 bf16x8 __attribute__((ext_vector_type(8)));
typedef float  f32x4  __attribute__((ext_vector_type(4)));

// ---- Kernel A: q = t@Wq^T, k = t@Wk^T (bf16), plus fused Wv->bf16. ----
__global__ __launch_bounds__(64) void qk_proj_bf16(
    const float* __restrict__ t,    // (B*N, 512)
    const float* __restrict__ Wq,   // (64, 512)
    const float* __restrict__ Wk,   // (64, 512)
    const float* __restrict__ Wv,   // (512, 64)
    __bf16* __restrict__ qb,        // (B*N, 64)
    __bf16* __restrict__ kb,        // (B*N, 64)
    __bf16* __restrict__ wvb)       // (512, 64)
{
    __shared__ float trow[DB];
    const int bn = blockIdx.x;
    const int e  = threadIdx.x;     // 0..63

    // fused Wv conversion: first 512 blocks convert one 64-elem row each
    if (bn < DB)
        wvb[bn * EB + e] = (__bf16)Wv[bn * EB + e];

    #pragma unroll
    for (int idx = 0; idx < DB / 64; ++idx)
        trow[idx * 64 + e] = t[(size_t)bn * DB + idx * 64 + e];
    __syncthreads();

    float aq = 0.f, ak = 0.f;
    const float* wqr = Wq + (size_t)e * DB;
    const float* wkr = Wk + (size_t)e * DB;
    #pragma unroll 8
    for (int d = 0; d < DB; ++d) {
        const float tv = trow[d];
        aq += tv * wqr[d];
        ak += tv * wkr[d];
    }
    qb[bn * EB + e] = (__bf16)aq;
    kb[bn * EB + e] = (__bf16)ak;
}

// ---- Kernel B (persistent, barrier-free, NONTEMPORAL stores): ----
// out[b,i,j,d] = sum_e k[b,j,e] * (q[b,i,e] * Wv[d,e])
// R7 structure: q folded into Wv fragments once per block; wave-private 8KB
// swizzled LDS; no __syncthreads. NEW: output stores are non-temporal (`nt`)
// -> no L2 allocate/dirty/evict churn, stream straight toward HBM.
__global__ __launch_bounds__(256) void kappa_mfma(
    const __bf16* __restrict__ qb,   // (B*N, 64)
    const __bf16* __restrict__ kb,   // (B*N, 64)
    const __bf16* __restrict__ wvb,  // (512, 64)  [d][e]
    float* __restrict__ out)         // (B*N, N, 512)
{
    const int blk = blockIdx.x;          // 0..2047
    const int bi  = blk >> 1;            // 0..1023  (= b*N + i)
    const int b   = bi >> 9;             // batch
    const int jt0 = (blk & 1) * TPB;     // tile base within the bi
    const int w    = threadIdx.x >> 6;   // wave 0..3 -> d-quarter
    const int l    = threadIdx.x & 63;
    const int lrow = l & 15;
    const int lgrp = l >> 4;             // e-chunk base = lgrp*8
    const int dbase = w * 128;

    __shared__ float lds[4 * JT * 128];  // 32 KB total; 8 KB per wave
    float* __restrict__ wtile = lds + w * (JT * 128);

    // q chunks (loop-invariant)
    const bf16x8 qv0 = *reinterpret_cast<const bf16x8*>(qb + (size_t)bi * EB + lgrp * 8);
    const bf16x8 qv1 = *reinterpret_cast<const bf16x8*>(qb + (size_t)bi * EB + 32 + lgrp * 8);

    // Wv fragments with q FOLDED IN (once per block). m=d, lane lrow = d%16.
    bf16x8 bfrag[8][2];
    #pragma unroll
    for (int df = 0; df < 8; ++df) {
        const int d = dbase + df * 16 + lrow;
        #pragma unroll
        for (int ks = 0; ks < 2; ++ks) {
            const bf16x8 wv = *reinterpret_cast<const bf16x8*>(
                wvb + (size_t)d * EB + ks * 32 + lgrp * 8);
            const bf16x8 qq = ks ? qv1 : qv0;
            bf16x8 f;
            #pragma unroll
            for (int x = 0; x < 8; ++x)
                f[x] = (__bf16)((float)wv[x] * (float)qq[x]);
            bfrag[df][ks] = f;
        }
    }

    const __bf16* __restrict__ kbase = kb + (size_t)b * NB * EB;

    // prefetch k rows for tile 0 (B-operand: lane lrow = j%16, raw k)
    bf16x8 kv0 = *reinterpret_cast<const bf16x8*>(kbase + (size_t)(jt0 * JT + lrow) * EB + lgrp * 8);
    bf16x8 kv1 = *reinterpret_cast<const bf16x8*>(kbase + (size_t)(jt0 * JT + lrow) * EB + 32 + lgrp * 8);

    const int r_lo = l >> 5;        // 0/1: epilogue row parity
    const int cc   = l & 31;        // epilogue d-chunk (16B units)

    for (int t = 0; t < TPB; ++t) {
        // MFMA: acc[df][r] = out[j=jb+lrow][d=dbase+df*16+lgrp*4+r]
        f32x4 acc[8];
        #pragma unroll
        for (int df = 0; df < 8; ++df) {
            acc[df] = (f32x4){0.f, 0.f, 0.f, 0.f};
            acc[df] = __builtin_amdgcn_mfma_f32_16x16x32_bf16(bfrag[df][0], kv0, acc[df], 0, 0, 0);
            acc[df] = __builtin_amdgcn_mfma_f32_16x16x32_bf16(bfrag[df][1], kv1, acc[df], 0, 0, 0);
        }

        // prefetch k for next tile (uniform branch)
        if (t + 1 < TPB) {
            const int jn = (jt0 + t + 1) * JT + lrow;
            kv0 = *reinterpret_cast<const bf16x8*>(kbase + (size_t)jn * EB + lgrp * 8);
            kv1 = *reinterpret_cast<const bf16x8*>(kbase + (size_t)jn * EB + 32 + lgrp * 8);
        }

        // acc -> wave-private LDS, XOR-16B swizzle (conflict-free both sides)
        asm volatile("" ::: "memory");
        #pragma unroll
        for (int df = 0; df < 8; ++df) {
            const int sc = (df * 4 + lgrp) ^ (lrow & 7);
            *reinterpret_cast<f32x4*>(wtile + lrow * 128 + sc * 4) = acc[df];
        }
        asm volatile("" ::: "memory");

        // read back linear + NONTEMPORAL store: 2 rows x 512B per pass
        float* __restrict__ obase =
            out + ((size_t)bi * NB + (size_t)(jt0 + t) * JT) * DB + dbase;
        #pragma unroll
        for (int p = 0; p < 8; ++p) {
            const int r  = 2 * p + r_lo;
            const int sc = cc ^ (r & 7);
            const f32x4 v = *reinterpret_cast<const f32x4*>(wtile + r * 128 + sc * 4);
            __builtin_nontemporal_store(
                v, reinterpret_cast<f32x4*>(obase + (size_t)r * DB + cc * 4));
        }
    }
}

extern "C" void kernel_launch(void* const* d_in, const int* in_sizes, int n_in,
                              void* d_out, int out_size, void* d_ws, size_t ws_size,
                              hipStream_t stream) {
    const float* t  = (const float*)d_in[0];  // (2,512,512)
    const float* Wq = (const float*)d_in[1];  // (64,512)
    const float* Wk = (const float*)d_in[2];  // (64,512)
    const float* Wv = (const float*)d_in[3];  // (512,64)
    float* out = (float*)d_out;

    const int B = 2;

    __bf16* qb  = (__bf16*)d_ws;                       // B*N*64
    __bf16* kbf = qb + (size_t)B * NB * EB;            // B*N*64
    __bf16* wvb = kbf + (size_t)B * NB * EB;           // 512*64

    qk_proj_bf16<<<dim3(B * NB), dim3(64), 0, stream>>>(t, Wq, Wk, Wv, qb, kbf, wvb);

    kappa_mfma<<<dim3(2048), dim3(256), 0, stream>>>(qb, kbf, wvb, out);
}

// Round 10
// 219.891 us; speedup vs baseline: 1.1013x; 1.0979x over previous
//
#include <hip/hip_runtime.h>
#include <hip/hip_bf16.h>

#define NB   512   // sequence length N
#define DB   512   // model dim D
#define EB   64    // d_dir
#define JT   16    // j-rows per tile
#define TPB  16    // tiles per block (block covers 256 rows = half a bi)

typedef __bf16 bf16x8 __attribute__((ext_vector_type(8)));
typedef float  f32x4  __attribute__((ext_vector_type(4)));

// ---- Kernel A: q = t@Wq^T, k = t@Wk^T (bf16) + fused Wv->bf16. ----
// 512 blocks x 64 thr; block handles 2 bn-rows (halves Wq/Wk L2 traffic) and
// converts 1 Wv row. t reads are wave-uniform -> scalar loads; Wq/Wk stream
// per-lane rows; 4 independent accum chains for ILP.
__global__ __launch_bounds__(64) void qk_proj_bf16(
    const float* __restrict__ t,    // (B*N, 512)
    const float* __restrict__ Wq,   // (64, 512)
    const float* __restrict__ Wk,   // (64, 512)
    const float* __restrict__ Wv,   // (512, 64)
    __bf16* __restrict__ qb,        // (B*N, 64)
    __bf16* __restrict__ kb,        // (B*N, 64)
    __bf16* __restrict__ wvb)       // (512, 64)
{
    const int blk = blockIdx.x;     // 0..511
    const int bn0 = blk * 2;
    const int e   = threadIdx.x;    // 0..63

    wvb[blk * EB + e] = (__bf16)Wv[blk * EB + e];

    float aq0 = 0.f, ak0 = 0.f, aq1 = 0.f, ak1 = 0.f;
    const float* __restrict__ wqr = Wq + (size_t)e * DB;
    const float* __restrict__ wkr = Wk + (size_t)e * DB;
    const float* __restrict__ t0  = t + (size_t)bn0 * DB;
    const float* __restrict__ t1  = t0 + DB;
    #pragma unroll 8
    for (int d = 0; d < DB; ++d) {
        const float wqv = wqr[d];
        const float wkv = wkr[d];
        const float tv0 = t0[d];    // uniform -> s_load
        const float tv1 = t1[d];
        aq0 += tv0 * wqv;  ak0 += tv0 * wkv;
        aq1 += tv1 * wqv;  ak1 += tv1 * wkv;
    }
    qb[(size_t)bn0 * EB + e]       = (__bf16)aq0;
    kb[(size_t)bn0 * EB + e]       = (__bf16)ak0;
    qb[(size_t)(bn0 + 1) * EB + e] = (__bf16)aq1;
    kb[(size_t)(bn0 + 1) * EB + e] = (__bf16)ak1;
}

// ---- Kernel B (persistent, barrier-free, DOUBLE-BUFFERED epilogue): ----
// out[b,i,j,d] = sum_e k[b,j,e] * (q[b,i,e] * Wv[d,e])
// R7 base: q folded into Wv frags once; wave-private swizzled LDS; no
// __syncthreads. NEW: tile loop manually unrolled 2x with TWO LDS buffers and
// separate epilogue register sets, so tile t's stores stay in flight through
// all of tile t+1's compute (vmcnt wait deferred to t+2) -> store issue is
// never gated by store-ack latency.
__global__ __launch_bounds__(256) void kappa_mfma(
    const __bf16* __restrict__ qb,   // (B*N, 64)
    const __bf16* __restrict__ kb,   // (B*N, 64)
    const __bf16* __restrict__ wvb,  // (512, 64)  [d][e]
    float* __restrict__ out)         // (B*N, N, 512)
{
    const int blk = blockIdx.x;          // 0..2047
    const int bi  = blk >> 1;            // 0..1023  (= b*N + i)
    const int b   = bi >> 9;             // batch
    const int jt0 = (blk & 1) * TPB;     // tile base within the bi
    const int w    = threadIdx.x >> 6;   // wave 0..3 -> d-quarter
    const int l    = threadIdx.x & 63;
    const int lrow = l & 15;
    const int lgrp = l >> 4;             // e-chunk base = lgrp*8
    const int dbase = w * 128;

    __shared__ float lds[2 * 4 * JT * 128];   // 64 KB: [parity][wave][16][128]
    float* __restrict__ wtA = lds + w * (JT * 128);
    float* __restrict__ wtB = lds + 4 * JT * 128 + w * (JT * 128);

    // q chunks (loop-invariant)
    const bf16x8 qv0 = *reinterpret_cast<const bf16x8*>(qb + (size_t)bi * EB + lgrp * 8);
    const bf16x8 qv1 = *reinterpret_cast<const bf16x8*>(qb + (size_t)bi * EB + 32 + lgrp * 8);

    // Wv fragments with q folded in (once per block). m=d, lane lrow = d%16.
    bf16x8 bfrag[8][2];
    #pragma unroll
    for (int df = 0; df < 8; ++df) {
        const int d = dbase + df * 16 + lrow;
        #pragma unroll
        for (int ks = 0; ks < 2; ++ks) {
            const bf16x8 wv = *reinterpret_cast<const bf16x8*>(
                wvb + (size_t)d * EB + ks * 32 + lgrp * 8);
            const bf16x8 qq = ks ? qv1 : qv0;
            bf16x8 f;
            #pragma unroll
            for (int x = 0; x < 8; ++x)
                f[x] = (__bf16)((float)wv[x] * (float)qq[x]);
            bfrag[df][ks] = f;
        }
    }

    const __bf16* __restrict__ kbase = kb + (size_t)b * NB * EB;

    // prefetch k rows for tile 0
    bf16x8 kv0 = *reinterpret_cast<const bf16x8*>(kbase + (size_t)(jt0 * JT + lrow) * EB + lgrp * 8);
    bf16x8 kv1 = *reinterpret_cast<const bf16x8*>(kbase + (size_t)(jt0 * JT + lrow) * EB + 32 + lgrp * 8);

    const int r_lo = l >> 5;        // 0/1: epilogue row parity
    const int cc   = l & 31;        // epilogue d-chunk (16B units)

    for (int t2 = 0; t2 < TPB; t2 += 2) {
        // ================= EVEN tile (t2) — buffer A =================
        {
            f32x4 acc[8];
            #pragma unroll
            for (int df = 0; df < 8; ++df) {
                acc[df] = (f32x4){0.f, 0.f, 0.f, 0.f};
                acc[df] = __builtin_amdgcn_mfma_f32_16x16x32_bf16(bfrag[df][0], kv0, acc[df], 0, 0, 0);
                acc[df] = __builtin_amdgcn_mfma_f32_16x16x32_bf16(bfrag[df][1], kv1, acc[df], 0, 0, 0);
            }
            // prefetch k for odd tile (t2+1 < TPB always, TPB even)
            {
                const int jn = (jt0 + t2 + 1) * JT + lrow;
                kv0 = *reinterpret_cast<const bf16x8*>(kbase + (size_t)jn * EB + lgrp * 8);
                kv1 = *reinterpret_cast<const bf16x8*>(kbase + (size_t)jn * EB + 32 + lgrp * 8);
            }
            asm volatile("" ::: "memory");
            #pragma unroll
            for (int df = 0; df < 8; ++df) {
                const int sc = (df * 4 + lgrp) ^ (lrow & 7);
                *reinterpret_cast<f32x4*>(wtA + lrow * 128 + sc * 4) = acc[df];
            }
            asm volatile("" ::: "memory");
            f32x4 ve[8];
            #pragma unroll
            for (int p = 0; p < 8; ++p) {
                const int r  = 2 * p + r_lo;
                const int sc = cc ^ (r & 7);
                ve[p] = *reinterpret_cast<const f32x4*>(wtA + r * 128 + sc * 4);
            }
            float* __restrict__ obase =
                out + ((size_t)bi * NB + (size_t)(jt0 + t2) * JT) * DB + dbase;
            #pragma unroll
            for (int p = 0; p < 8; ++p) {
                const int r = 2 * p + r_lo;
                *reinterpret_cast<f32x4*>(obase + (size_t)r * DB + cc * 4) = ve[p];
            }
        }
        // ================= ODD tile (t2+1) — buffer B =================
        {
            f32x4 acc[8];
            #pragma unroll
            for (int df = 0; df < 8; ++df) {
                acc[df] = (f32x4){0.f, 0.f, 0.f, 0.f};
                acc[df] = __builtin_amdgcn_mfma_f32_16x16x32_bf16(bfrag[df][0], kv0, acc[df], 0, 0, 0);
                acc[df] = __builtin_amdgcn_mfma_f32_16x16x32_bf16(bfrag[df][1], kv1, acc[df], 0, 0, 0);
            }
            if (t2 + 2 < TPB) {
                const int jn = (jt0 + t2 + 2) * JT + lrow;
                kv0 = *reinterpret_cast<const bf16x8*>(kbase + (size_t)jn * EB + lgrp * 8);
                kv1 = *reinterpret_cast<const bf16x8*>(kbase + (size_t)jn * EB + 32 + lgrp * 8);
            }
            asm volatile("" ::: "memory");
            #pragma unroll
            for (int df = 0; df < 8; ++df) {
                const int sc = (df * 4 + lgrp) ^ (lrow & 7);
                *reinterpret_cast<f32x4*>(wtB + lrow * 128 + sc * 4) = acc[df];
            }
            asm volatile("" ::: "memory");
            f32x4 vo[8];
            #pragma unroll
            for (int p = 0; p < 8; ++p) {
                const int r  = 2 * p + r_lo;
                const int sc = cc ^ (r & 7);
                vo[p] = *reinterpret_cast<const f32x4*>(wtB + r * 128 + sc * 4);
            }
            float* __restrict__ obase =
                out + ((size_t)bi * NB + (size_t)(jt0 + t2 + 1) * JT) * DB + dbase;
            #pragma unroll
            for (int p = 0; p < 8; ++p) {
                const int r = 2 * p + r_lo;
                *reinterpret_cast<f32x4*>(obase + (size_t)r * DB + cc * 4) = vo[p];
            }
        }
    }
}

extern "C" void kernel_launch(void* const* d_in, const int* in_sizes, int n_in,
                              void* d_out, int out_size, void* d_ws, size_t ws_size,
                              hipStream_t stream) {
    const float* t  = (const float*)d_in[0];  // (2,512,512)
    const float* Wq = (const float*)d_in[1];  // (64,512)
    const float* Wk = (const float*)d_in[2];  // (64,512)
    const float* Wv = (const float*)d_in[3];  // (512,64)
    float* out = (float*)d_out;

    const int B = 2;

    __bf16* qb  = (__bf16*)d_ws;                       // B*N*64
    __bf16* kbf = qb + (size_t)B * NB * EB;            // B*N*64
    __bf16* wvb = kbf + (size_t)B * NB * EB;           // 512*64

    qk_proj_bf16<<<dim3(512), dim3(64), 0, stream>>>(t, Wq, Wk, Wv, qb, kbf, wvb);

    kappa_mfma<<<dim3(2048), dim3(256), 0, stream>>>(qb, kbf, wvb, out);
}

// Round 11
// 218.894 us; speedup vs baseline: 1.1063x; 1.0046x over previous
//
#include <hip/hip_runtime.h>
#include <hip/hip_bf16.h>

#define NB   512   // sequence length N
#define DB   512   // model dim D
#define EB   64    // d_dir
#define JT   16    // j-rows per tile
#define TPB  16    // tiles per block (block covers 256 rows = half a bi)

typedef __bf16 bf16x8 __attribute__((ext_vector_type(8)));
typedef float  f32x4  __attribute__((ext_vector_type(4)));

// ---- Kernel A: q = t@Wq^T, k = t@Wk^T (bf16) + fused Wv->bf16. ----
__global__ __launch_bounds__(64) void qk_proj_bf16(
    const float* __restrict__ t,    // (B*N, 512)
    const float* __restrict__ Wq,   // (64, 512)
    const float* __restrict__ Wk,   // (64, 512)
    const float* __restrict__ Wv,   // (512, 64)
    __bf16* __restrict__ qb,        // (B*N, 64)
    __bf16* __restrict__ kb,        // (B*N, 64)
    __bf16* __restrict__ wvb)       // (512, 64)
{
    const int blk = blockIdx.x;     // 0..511
    const int bn0 = blk * 2;
    const int e   = threadIdx.x;    // 0..63

    wvb[blk * EB + e] = (__bf16)Wv[blk * EB + e];

    float aq0 = 0.f, ak0 = 0.f, aq1 = 0.f, ak1 = 0.f;
    const float* __restrict__ wqr = Wq + (size_t)e * DB;
    const float* __restrict__ wkr = Wk + (size_t)e * DB;
    const float* __restrict__ t0  = t + (size_t)bn0 * DB;
    const float* __restrict__ t1  = t0 + DB;
    #pragma unroll 8
    for (int d = 0; d < DB; ++d) {
        const float wqv = wqr[d];
        const float wkv = wkr[d];
        const float tv0 = t0[d];    // uniform -> s_load
        const float tv1 = t1[d];
        aq0 += tv0 * wqv;  ak0 += tv0 * wkv;
        aq1 += tv1 * wqv;  ak1 += tv1 * wkv;
    }
    qb[(size_t)bn0 * EB + e]       = (__bf16)aq0;
    kb[(size_t)bn0 * EB + e]       = (__bf16)ak0;
    qb[(size_t)(bn0 + 1) * EB + e] = (__bf16)aq1;
    kb[(size_t)(bn0 + 1) * EB + e] = (__bf16)ak1;
}

// ---- Kernel B (persistent, barrier-free, 2-deep store pipe, depth-8 k-prefetch) ----
// out[b,i,j,d] = sum_e k[b,j,e] * (q[b,i,e] * Wv[d,e])
// R10 base + ONE change: k fragments live in a rolling 8-tile register window
// (kreg[t&7], reloaded for tile t+8 right after tile t consumes it). No load
// is ever waited on with younger-store slack < ~8 tiles -> the shared vmcnt
// counter never forces a store drain on the critical path.
__global__ __launch_bounds__(256) void kappa_mfma(
    const __bf16* __restrict__ qb,   // (B*N, 64)
    const __bf16* __restrict__ kb,   // (B*N, 64)
    const __bf16* __restrict__ wvb,  // (512, 64)  [d][e]
    float* __restrict__ out)         // (B*N, N, 512)
{
    const int blk = blockIdx.x;          // 0..2047
    const int bi  = blk >> 1;            // 0..1023  (= b*N + i)
    const int b   = bi >> 9;             // batch
    const int jt0 = (blk & 1) * TPB;     // tile base within the bi
    const int w    = threadIdx.x >> 6;   // wave 0..3 -> d-quarter
    const int l    = threadIdx.x & 63;
    const int lrow = l & 15;
    const int lgrp = l >> 4;             // e-chunk base = lgrp*8
    const int dbase = w * 128;

    __shared__ float lds[2 * 4 * JT * 128];   // 64 KB: [parity][wave][16][128]
    float* __restrict__ wtA = lds + w * (JT * 128);
    float* __restrict__ wtB = lds + 4 * JT * 128 + w * (JT * 128);

    // q chunks (loop-invariant)
    const bf16x8 qv0 = *reinterpret_cast<const bf16x8*>(qb + (size_t)bi * EB + lgrp * 8);
    const bf16x8 qv1 = *reinterpret_cast<const bf16x8*>(qb + (size_t)bi * EB + 32 + lgrp * 8);

    // Wv fragments with q folded in (once per block). m=d, lane lrow = d%16.
    bf16x8 bfrag[8][2];
    #pragma unroll
    for (int df = 0; df < 8; ++df) {
        const int d = dbase + df * 16 + lrow;
        #pragma unroll
        for (int ks = 0; ks < 2; ++ks) {
            const bf16x8 wv = *reinterpret_cast<const bf16x8*>(
                wvb + (size_t)d * EB + ks * 32 + lgrp * 8);
            const bf16x8 qq = ks ? qv1 : qv0;
            bf16x8 f;
            #pragma unroll
            for (int x = 0; x < 8; ++x)
                f[x] = (__bf16)((float)wv[x] * (float)qq[x]);
            bfrag[df][ks] = f;
        }
    }

    const __bf16* __restrict__ kbase = kb + (size_t)b * NB * EB;

    // depth-8 k prefetch window: kreg[t&7] holds tile t's two bf16x8 chunks
    bf16x8 kreg[8][2];
    #pragma unroll
    for (int t = 0; t < 8; ++t) {
        const int jn = (jt0 + t) * JT + lrow;
        kreg[t][0] = *reinterpret_cast<const bf16x8*>(kbase + (size_t)jn * EB + lgrp * 8);
        kreg[t][1] = *reinterpret_cast<const bf16x8*>(kbase + (size_t)jn * EB + 32 + lgrp * 8);
    }

    const int r_lo = l >> 5;        // 0/1: epilogue row parity
    const int cc   = l & 31;        // epilogue d-chunk (16B units)

    #pragma unroll
    for (int t = 0; t < TPB; ++t) {
        const int slot = t & 7;

        // MFMA: acc[df][r] = out[j=jb+lrow][d=dbase+df*16+lgrp*4+r]
        f32x4 acc[8];
        #pragma unroll
        for (int df = 0; df < 8; ++df) {
            acc[df] = (f32x4){0.f, 0.f, 0.f, 0.f};
            acc[df] = __builtin_amdgcn_mfma_f32_16x16x32_bf16(bfrag[df][0], kreg[slot][0], acc[df], 0, 0, 0);
            acc[df] = __builtin_amdgcn_mfma_f32_16x16x32_bf16(bfrag[df][1], kreg[slot][1], acc[df], 0, 0, 0);
        }

        // reload this slot for tile t+8 (8-tile lead time)
        if (t < 8) {
            const int jn = (jt0 + t + 8) * JT + lrow;
            kreg[slot][0] = *reinterpret_cast<const bf16x8*>(kbase + (size_t)jn * EB + lgrp * 8);
            kreg[slot][1] = *reinterpret_cast<const bf16x8*>(kbase + (size_t)jn * EB + 32 + lgrp * 8);
        }

        float* __restrict__ wtile = (t & 1) ? wtB : wtA;

        // acc -> wave-private LDS, XOR-16B swizzle (conflict-free both sides)
        asm volatile("" ::: "memory");
        #pragma unroll
        for (int df = 0; df < 8; ++df) {
            const int sc = (df * 4 + lgrp) ^ (lrow & 7);
            *reinterpret_cast<f32x4*>(wtile + lrow * 128 + sc * 4) = acc[df];
        }
        asm volatile("" ::: "memory");

        // read back linear, then store (2 rows x 512B segments per pass)
        f32x4 ve[8];
        #pragma unroll
        for (int p = 0; p < 8; ++p) {
            const int r  = 2 * p + r_lo;
            const int sc = cc ^ (r & 7);
            ve[p] = *reinterpret_cast<const f32x4*>(wtile + r * 128 + sc * 4);
        }
        float* __restrict__ obase =
            out + ((size_t)bi * NB + (size_t)(jt0 + t) * JT) * DB + dbase;
        #pragma unroll
        for (int p = 0; p < 8; ++p) {
            const int r = 2 * p + r_lo;
            *reinterpret_cast<f32x4*>(obase + (size_t)r * DB + cc * 4) = ve[p];
        }
    }
}

extern "C" void kernel_launch(void* const* d_in, const int* in_sizes, int n_in,
                              void* d_out, int out_size, void* d_ws, size_t ws_size,
                              hipStream_t stream) {
    const float* t  = (const float*)d_in[0];  // (2,512,512)
    const float* Wq = (const float*)d_in[1];  // (64,512)
    const float* Wk = (const float*)d_in[2];  // (64,512)
    const float* Wv = (const float*)d_in[3];  // (512,64)
    float* out = (float*)d_out;

    const int B = 2;

    __bf16* qb  = (__bf16*)d_ws;                       // B*N*64
    __bf16* kbf = qb + (size_t)B * NB * EB;            // B*N*64
    __bf16* wvb = kbf + (size_t)B * NB * EB;           // 512*64

    qk_proj_bf16<<<dim3(512), dim3(64), 0, stream>>>(t, Wq, Wk, Wv, qb, kbf, wvb);

    kappa_mfma<<<dim3(2048), dim3(256), 0, stream>>>(qb, kbf, wvb, out);
}

// Round 12
// 215.875 us; speedup vs baseline: 1.1217x; 1.0140x over previous
//
#include <hip/hip_runtime.h>
#include <hip/hip_bf16.h>

#define NB   512   // sequence length N
#define DB   512   // model dim D
#define EB   64    // d_dir
#define JT   16    // j-rows per tile
#define TPB  16    // tiles per block (block covers 256 rows = half a bi)
#define PR   8     // bn-rows per proj block
#define WSTR 65    // LDS stride for transposed W chunks (65 % 32 == 1 -> conflict-free)

typedef __bf16 bf16x8 __attribute__((ext_vector_type(8)));
typedef float  f32x4  __attribute__((ext_vector_type(4)));

// ---- Kernel A: q = t@Wq^T, k = t@Wk^T (bf16) + fused Wv->bf16. ----
// 128 blocks x 256 thr; block = 8 bn-rows (wave w -> rows 2w, 2w+1).
// Per 64-d chunk: Wq/Wk loaded COALESCED (float4) and stored transposed into
// LDS [d'][e] stride 65 (writes: banks (d'+e) mod 32, 2-way max; reads: lane e
// -> bank (dp+e) mod 32, 2-way max -> free). Kills the 2KB-stride per-lane
// global streams (536MB effective L2 traffic -> 33MB).
__global__ __launch_bounds__(256) void qk_proj_bf16(
    const float* __restrict__ t,    // (B*N, 512)
    const float* __restrict__ Wq,   // (64, 512)
    const float* __restrict__ Wk,   // (64, 512)
    const float* __restrict__ Wv,   // (512, 64)
    __bf16* __restrict__ qb,        // (B*N, 64)
    __bf16* __restrict__ kb,        // (B*N, 64)
    __bf16* __restrict__ wvb)       // (512, 64)
{
    const int blk = blockIdx.x;     // 0..127
    const int bn0 = blk * PR;
    const int tid = threadIdx.x;
    const int e   = tid & 63;       // lane -> output e
    const int w   = tid >> 6;       // wave 0..3 -> rows 2w, 2w+1

    __shared__ float wqt[64 * WSTR];   // [d'][e], stride 65
    __shared__ float wkt[64 * WSTR];

    // fused Wv conversion: 4 rows per block (128*4 = 512 rows)
    {
        const int r = blk * 4 + w;
        wvb[r * EB + e] = (__bf16)Wv[r * EB + e];
    }

    float aq0 = 0.f, ak0 = 0.f, aq1 = 0.f, ak1 = 0.f;
    const float* __restrict__ t0 = t + (size_t)(bn0 + 2 * w) * DB;  // uniform -> s_load
    const float* __restrict__ t1 = t0 + DB;

    const int er = tid >> 4;           // 0..15 (loader row group)
    const int dd = (tid & 15) * 4;     // 0..60 (loader d offset)

    for (int c = 0; c < 8; ++c) {
        const int d0 = c * 64;
        __syncthreads();               // previous chunk's reads complete

        // cooperative coalesced load + LDS transpose: 4 e-rows per thread
        #pragma unroll
        for (int g = 0; g < 4; ++g) {
            const int erow = er + g * 16;
            const f32x4 vq = *reinterpret_cast<const f32x4*>(Wq + (size_t)erow * DB + d0 + dd);
            const f32x4 vk = *reinterpret_cast<const f32x4*>(Wk + (size_t)erow * DB + d0 + dd);
            #pragma unroll
            for (int i = 0; i < 4; ++i) {
                wqt[(dd + i) * WSTR + erow] = vq[i];
                wkt[(dd + i) * WSTR + erow] = vk[i];
            }
        }
        __syncthreads();

        // accumulate: lane e, rows 2w / 2w+1
        #pragma unroll 8
        for (int dp = 0; dp < 64; ++dp) {
            const float tq  = wqt[dp * WSTR + e];
            const float tk  = wkt[dp * WSTR + e];
            const float tv0 = t0[d0 + dp];     // uniform scalar load
            const float tv1 = t1[d0 + dp];
            aq0 += tv0 * tq;  ak0 += tv0 * tk;
            aq1 += tv1 * tq;  ak1 += tv1 * tk;
        }
    }

    const size_t r0 = (size_t)(bn0 + 2 * w) * EB + e;
    qb[r0]      = (__bf16)aq0;
    kb[r0]      = (__bf16)ak0;
    qb[r0 + EB] = (__bf16)aq1;
    kb[r0 + EB] = (__bf16)ak1;
}

// ---- Kernel B (persistent, barrier-free, 2-deep store pipe, depth-8 k-prefetch) ----
// (byte-identical to R11 — best measured: 219 us)
__global__ __launch_bounds__(256) void kappa_mfma(
    const __bf16* __restrict__ qb,   // (B*N, 64)
    const __bf16* __restrict__ kb,   // (B*N, 64)
    const __bf16* __restrict__ wvb,  // (512, 64)  [d][e]
    float* __restrict__ out)         // (B*N, N, 512)
{
    const int blk = blockIdx.x;          // 0..2047
    const int bi  = blk >> 1;            // 0..1023  (= b*N + i)
    const int b   = bi >> 9;             // batch
    const int jt0 = (blk & 1) * TPB;     // tile base within the bi
    const int w    = threadIdx.x >> 6;   // wave 0..3 -> d-quarter
    const int l    = threadIdx.x & 63;
    const int lrow = l & 15;
    const int lgrp = l >> 4;             // e-chunk base = lgrp*8
    const int dbase = w * 128;

    __shared__ float lds[2 * 4 * JT * 128];   // 64 KB: [parity][wave][16][128]
    float* __restrict__ wtA = lds + w * (JT * 128);
    float* __restrict__ wtB = lds + 4 * JT * 128 + w * (JT * 128);

    // q chunks (loop-invariant)
    const bf16x8 qv0 = *reinterpret_cast<const bf16x8*>(qb + (size_t)bi * EB + lgrp * 8);
    const bf16x8 qv1 = *reinterpret_cast<const bf16x8*>(qb + (size_t)bi * EB + 32 + lgrp * 8);

    // Wv fragments with q folded in (once per block). m=d, lane lrow = d%16.
    bf16x8 bfrag[8][2];
    #pragma unroll
    for (int df = 0; df < 8; ++df) {
        const int d = dbase + df * 16 + lrow;
        #pragma unroll
        for (int ks = 0; ks < 2; ++ks) {
            const bf16x8 wv = *reinterpret_cast<const bf16x8*>(
                wvb + (size_t)d * EB + ks * 32 + lgrp * 8);
            const bf16x8 qq = ks ? qv1 : qv0;
            bf16x8 f;
            #pragma unroll
            for (int x = 0; x < 8; ++x)
                f[x] = (__bf16)((float)wv[x] * (float)qq[x]);
            bfrag[df][ks] = f;
        }
    }

    const __bf16* __restrict__ kbase = kb + (size_t)b * NB * EB;

    // depth-8 k prefetch window: kreg[t&7] holds tile t's two bf16x8 chunks
    bf16x8 kreg[8][2];
    #pragma unroll
    for (int t = 0; t < 8; ++t) {
        const int jn = (jt0 + t) * JT + lrow;
        kreg[t][0] = *reinterpret_cast<const bf16x8*>(kbase + (size_t)jn * EB + lgrp * 8);
        kreg[t][1] = *reinterpret_cast<const bf16x8*>(kbase + (size_t)jn * EB + 32 + lgrp * 8);
    }

    const int r_lo = l >> 5;        // 0/1: epilogue row parity
    const int cc   = l & 31;        // epilogue d-chunk (16B units)

    #pragma unroll
    for (int t = 0; t < TPB; ++t) {
        const int slot = t & 7;

        // MFMA: acc[df][r] = out[j=jb+lrow][d=dbase+df*16+lgrp*4+r]
        f32x4 acc[8];
        #pragma unroll
        for (int df = 0; df < 8; ++df) {
            acc[df] = (f32x4){0.f, 0.f, 0.f, 0.f};
            acc[df] = __builtin_amdgcn_mfma_f32_16x16x32_bf16(bfrag[df][0], kreg[slot][0], acc[df], 0, 0, 0);
            acc[df] = __builtin_amdgcn_mfma_f32_16x16x32_bf16(bfrag[df][1], kreg[slot][1], acc[df], 0, 0, 0);
        }

        // reload this slot for tile t+8 (8-tile lead time)
        if (t < 8) {
            const int jn = (jt0 + t + 8) * JT + lrow;
            kreg[slot][0] = *reinterpret_cast<const bf16x8*>(kbase + (size_t)jn * EB + lgrp * 8);
            kreg[slot][1] = *reinterpret_cast<const bf16x8*>(kbase + (size_t)jn * EB + 32 + lgrp * 8);
        }

        float* __restrict__ wtile = (t & 1) ? wtB : wtA;

        // acc -> wave-private LDS, XOR-16B swizzle (conflict-free both sides)
        asm volatile("" ::: "memory");
        #pragma unroll
        for (int df = 0; df < 8; ++df) {
            const int sc = (df * 4 + lgrp) ^ (lrow & 7);
            *reinterpret_cast<f32x4*>(wtile + lrow * 128 + sc * 4) = acc[df];
        }
        asm volatile("" ::: "memory");

        // read back linear, then store (2 rows x 512B segments per pass)
        f32x4 ve[8];
        #pragma unroll
        for (int p = 0; p < 8; ++p) {
            const int r  = 2 * p + r_lo;
            const int sc = cc ^ (r & 7);
            ve[p] = *reinterpret_cast<const f32x4*>(wtile + r * 128 + sc * 4);
        }
        float* __restrict__ obase =
            out + ((size_t)bi * NB + (size_t)(jt0 + t) * JT) * DB + dbase;
        #pragma unroll
        for (int p = 0; p < 8; ++p) {
            const int r = 2 * p + r_lo;
            *reinterpret_cast<f32x4*>(obase + (size_t)r * DB + cc * 4) = ve[p];
        }
    }
}

extern "C" void kernel_launch(void* const* d_in, const int* in_sizes, int n_in,
                              void* d_out, int out_size, void* d_ws, size_t ws_size,
                              hipStream_t stream) {
    const float* t  = (const float*)d_in[0];  // (2,512,512)
    const float* Wq = (const float*)d_in[1];  // (64,512)
    const float* Wk = (const float*)d_in[2];  // (64,512)
    const float* Wv = (const float*)d_in[3];  // (512,64)
    float* out = (float*)d_out;

    const int B = 2;

    __bf16* qb  = (__bf16*)d_ws;                       // B*N*64
    __bf16* kbf = qb + (size_t)B * NB * EB;            // B*N*64
    __bf16* wvb = kbf + (size_t)B * NB * EB;           // 512*64

    qk_proj_bf16<<<dim3(128), dim3(256), 0, stream>>>(t, Wq, Wk, Wv, qb, kbf, wvb);

    kappa_mfma<<<dim3(2048), dim3(256), 0, stream>>>(qb, kbf, wvb, out);
}